// Round 2
// baseline (24.357 us; speedup 1.0000x reference)
//
#include <hip/hip_runtime.h>
#include <math.h>

typedef _Float16 f16x8 __attribute__((ext_vector_type(8)));
typedef float    f32x4 __attribute__((ext_vector_type(4)));

#define SCRW 132           // 128 + 4 pad
#define IMG_F 784
#define CHUNK_F 3136       // 4 images * 784 floats

typedef __attribute__((address_space(3))) void lds_void;
typedef const __attribute__((address_space(1))) void glb_void;

__device__ __forceinline__ f32x4 mfma16(f16x8 a, f16x8 b, f32x4 c) {
  return __builtin_amdgcn_mfma_f32_16x16x32_f16(a, b, c, 0, 0, 0);
}

// 8 contiguous f32 -> hi/lo f16 fragments (hi+lo ~= exact)
__device__ __forceinline__ void splitP(const float* p, f16x8& hi, f16x8& lo) {
  const f32x4* q = (const f32x4*)p;
  f32x4 a0 = q[0], a1 = q[1];
#pragma unroll
  for (int j = 0; j < 4; ++j) {
    _Float16 h0 = (_Float16)a0[j], h1 = (_Float16)a1[j];
    hi[j] = h0; hi[j + 4] = h1;
    lo[j]     = (_Float16)(a0[j] - (float)h0);
    lo[j + 4] = (_Float16)(a1[j] - (float)h1);
  }
}

// 8 strided f32 -> hi/lo f16 fragments
__device__ __forceinline__ void splitS(const float* p, int stride, f16x8& hi, f16x8& lo) {
#pragma unroll
  for (int j = 0; j < 8; ++j) {
    float x = p[j * stride];
    _Float16 h = (_Float16)x;
    hi[j] = h;
    lo[j] = (_Float16)(x - (float)h);
  }
}

// 8 contiguous f32 -> single-f16 B fragment (classifier weights)
__device__ __forceinline__ f16x8 bfrag8(const float* p) {
  const f32x4* q = (const f32x4*)p;
  f32x4 w0 = q[0], w1 = q[1];
  f16x8 b;
#pragma unroll
  for (int j = 0; j < 4; ++j) { b[j] = (_Float16)w0[j]; b[j + 4] = (_Float16)w1[j]; }
  return b;
}

// stream one 4-image chunk (12544 B) global -> LDS, coalesced
__device__ __forceinline__ void load_chunk(const float* gsrc, float* lbase, int l) {
#pragma unroll
  for (int i = 0; i < 12; ++i)
    __builtin_amdgcn_global_load_lds((glb_void*)(gsrc + i * 256 + l * 4),
                                     (lds_void*)(lbase + i * 256), 16, 0, 0);
  __builtin_amdgcn_global_load_lds((glb_void*)(gsrc + 3072 + l),
                                   (lds_void*)(lbase + 3072), 4, 0, 0);
}

__global__ __launch_bounds__(256) void mnist_cols(
    const float* __restrict__ img,  const float* __restrict__ Wff,
    const float* __restrict__ Wfb,  const float* __restrict__ Wvel,
    const float* __restrict__ Wc1,  const float* __restrict__ bc1,
    const float* __restrict__ Wc2,  const float* __restrict__ bc2,
    float* __restrict__ out) {
  __shared__ float img_lds[4][CHUNK_F];      // 50 KB: per-wave 4-image chunk
  __shared__ float scr_all[4][16 * SCRW];    // 33 KB: per-wave transpose scratch

  const int tid = threadIdx.x;
  const int wv = tid >> 6, l = tid & 63;
  const int g = l >> 4, c0 = l & 15, c1 = c0 + 16;
  float* scr  = scr_all[wv];
  float* ibuf = img_lds[wv];
  const int s0 = blockIdx.x * 64 + wv * 16;

  // ---- interp taps (never clipped; hi = lo+1) ----
  const float pos0 = 24.5f * (float)c0 + 11.75f;
  const float pos1 = 24.5f * (float)c1 + 11.75f;
  const int lo0 = (int)pos0, lo1 = (int)pos1;
  const float w0 = pos0 - (float)lo0, w1 = pos1 - (float)lo1;
  const int ta0 = (lo0 % 28) * 28 + lo0 / 28;
  const int tb0 = ((lo0 + 1) % 28) * 28 + (lo0 + 1) / 28;
  const int ta1 = (lo1 % 28) * 28 + lo1 / 28;
  const int tb1 = ((lo1 + 1) % 28) * 28 + (lo1 + 1) / 28;

  // ---- weight fragments (hi+lo). B-frags: row reads; A-frags of Wfb^T: strided ----
  f16x8 bfbh0, bfbl0, bfbh1, bfbl1, bffh0, bffl0, bffh1, bffl1;
  splitP(Wfb + c0 * 32 + g * 8, bfbh0, bfbl0);
  splitP(Wfb + c1 * 32 + g * 8, bfbh1, bfbl1);
  splitP(Wff + c0 * 32 + g * 8, bffh0, bffl0);
  splitP(Wff + c1 * 32 + g * 8, bffh1, bffl1);
  f16x8 afbh0, afbl0, afbh1, afbl1;
  splitS(Wfb + g * 256 + c0,      32, afbh0, afbl0);   // m-block 0
  splitS(Wfb + g * 256 + c0 + 16, 32, afbh1, afbl1);   // m-block 1
  const float wva0 = Wvel[c0 * 2], wva1 = Wvel[c0 * 2 + 1];
  const float wvb0 = Wvel[c1 * 2], wvb1 = Wvel[c1 * 2 + 1];

  // ---- start streaming chunk 0 while we build M ----
  load_chunk(img + (size_t)s0 * IMG_F, ibuf, l);

  // ---- M = Wfb^T @ Wff^T  (f32-accurate via 3-term hi/lo MFMA) ----
  const f32x4 zero = {0.f, 0.f, 0.f, 0.f};
  f32x4 m00 = mfma16(afbh0, bffl0, mfma16(afbl0, bffh0, mfma16(afbh0, bffh0, zero)));
  f32x4 m01 = mfma16(afbh0, bffl1, mfma16(afbl0, bffh1, mfma16(afbh0, bffh1, zero)));
  f32x4 m10 = mfma16(afbh1, bffl0, mfma16(afbl1, bffh0, mfma16(afbh1, bffh0, zero)));
  f32x4 m11 = mfma16(afbh1, bffl1, mfma16(afbl1, bffh1, mfma16(afbh1, bffh1, zero)));
#pragma unroll
  for (int r = 0; r < 4; ++r) {
    scr[(g * 4 + r) * 32 + c0]            = m00[r];
    scr[(g * 4 + r) * 32 + c0 + 16]       = m01[r];
    scr[(16 + g * 4 + r) * 32 + c0]       = m10[r];
    scr[(16 + g * 4 + r) * 32 + c0 + 16]  = m11[r];
  }
  f16x8 mbh0, mbl0, mbh1, mbl1;   // B-frags of M
  splitS(scr + g * 256 + c0,      32, mbh0, mbl0);
  splitS(scr + g * 256 + c0 + 16, 32, mbh1, mbl1);

  // ---- stream remaining chunks; extract taps per chunk ----
  float sens[4][2] = {}, td[4][2] = {};
#pragma unroll
  for (int c = 0; c < 4; ++c) {
    asm volatile("s_waitcnt vmcnt(0)" ::: "memory");
    __builtin_amdgcn_sched_barrier(0);
    if (g == c) {
#pragma unroll
      for (int r = 0; r < 4; ++r) {
        const float* base = ibuf + r * IMG_F;
        float sa0 = base[lo0], sa1 = base[lo0 + 1];
        float sb0 = base[lo1], sb1 = base[lo1 + 1];
        float t00 = base[ta0], t01 = base[tb0];
        float t10 = base[ta1], t11 = base[tb1];
        sens[r][0] = (sa0 * (1.0f - w0) + sa1 * w0) * 80.0f;
        sens[r][1] = (sb0 * (1.0f - w1) + sb1 * w1) * 80.0f;
        td[r][0]   = (t00 * (1.0f - w0) + t01 * w0) * 40.0f;
        td[r][1]   = (t10 * (1.0f - w1) + t11 * w1) * 40.0f;
      }
    }
    if (c < 3) load_chunk(img + (size_t)(s0 + (c + 1) * 4) * IMG_F, ibuf, l);
  }

  f16x8 ahi, alo;
  // ---- y_fb = relu(td @ Wfb^T) ----
#pragma unroll
  for (int r = 0; r < 4; ++r) {
    int row = (g * 4 + r) * SCRW;
    scr[row + c0] = td[r][0];
    scr[row + c1] = td[r][1];
  }
  splitP(scr + c0 * SCRW + g * 8, ahi, alo);
  f32x4 f0 = mfma16(ahi, bfbl0, mfma16(alo, bfbh0, mfma16(ahi, bfbh0, zero)));
  f32x4 f1 = mfma16(ahi, bfbl1, mfma16(alo, bfbh1, mfma16(ahi, bfbh1, zero)));
  float yfb[4][2];
#pragma unroll
  for (int r = 0; r < 4; ++r) { yfb[r][0] = fmaxf(f0[r], 0.f); yfb[r][1] = fmaxf(f1[r], 0.f); }

  // ---- s_ff = sens @ Wff^T (constant across steps) ----
#pragma unroll
  for (int r = 0; r < 4; ++r) {
    int row = (g * 4 + r) * SCRW;
    scr[row + c0] = sens[r][0];
    scr[row + c1] = sens[r][1];
  }
  splitP(scr + c0 * SCRW + g * 8, ahi, alo);
  f32x4 sff0 = mfma16(ahi, bffl0, mfma16(alo, bffh0, mfma16(ahi, bffh0, zero)));
  f32x4 sff1 = mfma16(ahi, bffl1, mfma16(alo, bffh1, mfma16(ahi, bffh1, zero)));

  // ---- merged recurrence: y_ff = relu(s_ff - r6@M); r6 += 0.1(-r6+y_ff+y_fb+vin) ----
  float r6[4][2] = {}, d[4][2] = {}, yff[4][2] = {};
  const float VX[3] = {0.2f, 0.0f, 0.15f};
  const float VY[3] = {0.0f, 0.2f, 0.15f};
#pragma unroll
  for (int v = 0; v < 3; ++v) {
    float vin[2];
    vin[0] = wva0 * VX[v] + wva1 * VY[v];
    vin[1] = wvb0 * VX[v] + wvb1 * VY[v];
#pragma unroll
    for (int st = 0; st < 3; ++st) {
      // transpose NEGATED r6 (so MFMA accumulates s_ff - r6@M)
#pragma unroll
      for (int r = 0; r < 4; ++r) {
        int row = (g * 4 + r) * SCRW;
        scr[row + c0] = -r6[r][0];
        scr[row + c1] = -r6[r][1];
      }
      splitP(scr + c0 * SCRW + g * 8, ahi, alo);
      f32x4 y0 = mfma16(ahi, mbl0, mfma16(alo, mbh0, mfma16(ahi, mbh0, sff0)));
      f32x4 y1 = mfma16(ahi, mbl1, mfma16(alo, mbh1, mfma16(ahi, mbh1, sff1)));
      if (v == 2 && st == 2) {
        // reconstruct d = sens - r6@Wfb^T for the final feature (A holds -r6)
        f32x4 t0 = mfma16(ahi, bfbl0, mfma16(alo, bfbh0, mfma16(ahi, bfbh0, zero)));
        f32x4 t1 = mfma16(ahi, bfbl1, mfma16(alo, bfbh1, mfma16(ahi, bfbh1, zero)));
#pragma unroll
        for (int r = 0; r < 4; ++r) { d[r][0] = sens[r][0] + t0[r]; d[r][1] = sens[r][1] + t1[r]; }
      }
#pragma unroll
      for (int r = 0; r < 4; ++r) {
        yff[r][0] = fmaxf(y0[r], 0.f);
        yff[r][1] = fmaxf(y1[r], 0.f);
        r6[r][0] += 0.1f * (yff[r][0] - r6[r][0] + yfb[r][0] + vin[0]);
        r6[r][1] += 0.1f * (yff[r][1] - r6[r][1] + yfb[r][1] + vin[1]);
      }
    }
  }

  // ---- feature = [y_ff | y_fb | r6 | |d|] ----
#pragma unroll
  for (int r = 0; r < 4; ++r) {
    int row = (g * 4 + r) * SCRW;
    scr[row +      c0] = yff[r][0];        scr[row +      c1] = yff[r][1];
    scr[row + 32 + c0] = yfb[r][0];        scr[row + 32 + c1] = yfb[r][1];
    scr[row + 64 + c0] = r6[r][0];         scr[row + 64 + c1] = r6[r][1];
    scr[row + 96 + c0] = fabsf(d[r][0]);   scr[row + 96 + c1] = fabsf(d[r][1]);
  }
  f32x4 acc0 = zero, acc1 = zero, acc2 = zero, acc3 = zero;
#pragma unroll
  for (int kb = 0; kb < 4; ++kb) {
    f16x8 fhi, flo;
    splitP(scr + c0 * SCRW + kb * 32 + g * 8, fhi, flo);
    const int ko = kb * 32 + g * 8;
    f16x8 b0 = bfrag8(Wc1 + (size_t)(c0)      * 128 + ko);
    f16x8 b1 = bfrag8(Wc1 + (size_t)(16 + c0) * 128 + ko);
    f16x8 b2 = bfrag8(Wc1 + (size_t)(32 + c0) * 128 + ko);
    f16x8 b3 = bfrag8(Wc1 + (size_t)(48 + c0) * 128 + ko);
    acc0 = mfma16(flo, b0, mfma16(fhi, b0, acc0));
    acc1 = mfma16(flo, b1, mfma16(fhi, b1, acc1));
    acc2 = mfma16(flo, b2, mfma16(fhi, b2, acc2));
    acc3 = mfma16(flo, b3, mfma16(fhi, b3, acc3));
  }
  float h[4][4];
  const float B0 = bc1[c0], B1 = bc1[16 + c0], B2 = bc1[32 + c0], B3 = bc1[48 + c0];
#pragma unroll
  for (int r = 0; r < 4; ++r) {
    float x0 = acc0[r] + B0, x1 = acc1[r] + B1, x2 = acc2[r] + B2, x3 = acc3[r] + B3;
    h[r][0] = 0.5f * x0 * (1.0f + erff(x0 * 0.70710678118654752f));
    h[r][1] = 0.5f * x1 * (1.0f + erff(x1 * 0.70710678118654752f));
    h[r][2] = 0.5f * x2 * (1.0f + erff(x2 * 0.70710678118654752f));
    h[r][3] = 0.5f * x3 * (1.0f + erff(x3 * 0.70710678118654752f));
  }

  // ---- logits = h @ Wc2^T + bc2 ----
#pragma unroll
  for (int r = 0; r < 4; ++r) {
    int row = (g * 4 + r) * SCRW;
#pragma unroll
    for (int nb = 0; nb < 4; ++nb) scr[row + nb * 16 + c0] = h[r][nb];
  }
  f32x4 accL = zero;
#pragma unroll
  for (int kb = 0; kb < 2; ++kb) {
    f16x8 hhi, hlo;
    splitP(scr + c0 * SCRW + kb * 32 + g * 8, hhi, hlo);
    f16x8 b;
    if (c0 < 10) {
      b = bfrag8(Wc2 + (size_t)c0 * 64 + kb * 32 + g * 8);
    } else {
#pragma unroll
      for (int j = 0; j < 8; ++j) b[j] = (_Float16)0.f;
    }
    accL = mfma16(hlo, b, mfma16(hhi, b, accL));
  }
  if (c0 < 10) {
    const float bb = bc2[c0];
#pragma unroll
    for (int r = 0; r < 4; ++r)
      out[(size_t)(s0 + g * 4 + r) * 10 + c0] = accL[r] + bb;
  }
}

extern "C" void kernel_launch(void* const* d_in, const int* in_sizes, int n_in,
                              void* d_out, int out_size, void* d_ws, size_t ws_size,
                              hipStream_t stream) {
  const float* img  = (const float*)d_in[0];
  const float* Wff  = (const float*)d_in[1];
  const float* Wfb  = (const float*)d_in[2];
  const float* Wvel = (const float*)d_in[3];
  const float* Wc1  = (const float*)d_in[4];
  const float* bc1  = (const float*)d_in[5];
  const float* Wc2  = (const float*)d_in[6];
  const float* bc2  = (const float*)d_in[7];
  float* out = (float*)d_out;
  const int B = in_sizes[0] / 784;     // 16384
  const int grid = B / 64;             // 64 samples / block (4 waves x 16)
  hipLaunchKernelGGL(mnist_cols, dim3(grid), dim3(256), 0, stream,
                     img, Wff, Wfb, Wvel, Wc1, bc1, Wc2, bc2, out);
}